// Round 9
// baseline (715.634 us; speedup 1.0000x reference)
//
#include <hip/hip_runtime.h>

// ---------------------------------------------------------------------------
// QuaternionLinear == one dense GEMM: out[M,N] = x[M,K] @ W_eff[N,K]^T + bias
//   M = 16384 (B*S), N = 2048 (OUT_F), K = 2048 (IN_F)
// Pipeline: prep (fp32->bf16 x + build W_eff) ; qgemm.
// qgemm: 256x256 tile, BK=64, 8 waves (2x4), per-wave 128x64 (R7 shape —
// R8's 4x4 grid raised LDS reads 192->256/tile and regressed).
// R9: WAVE STAGGER. Waves 0-3 run clusters (ks0,mh0)(ks0,mh1)(ks1,mh0)
// (ks1,mh1); waves 4-7 run (ks1,*) first. Each SIMD hosts wid s and s+4 ->
// read bursts of one wave overlap MFMA clusters of the other, de-serializing
// the LDS and matrix pipes (R5-R7 showed ~1850 cyc/tile lost to identical-
// program coincidence). T5 setprio around MFMA clusters now that waves have
// role-split (m218b). Stages bound to execution position -> vmcnt ledger
// unchanged. Kept: A 2-ring + B 3-ring LDS (160KB), chunk-XOR swizzle (T2),
// single end-of-tile sync w/ counted vmcnt(4) (T3/T4), literal ring indices,
// XCD swizzle (T1), fused prep.
// ---------------------------------------------------------------------------

typedef unsigned short u16;
typedef __bf16 bf16x8 __attribute__((ext_vector_type(8)));
typedef float f32x4 __attribute__((ext_vector_type(4)));

#define QM 16384
#define QN 2048
#define QK 2048

__device__ __forceinline__ u16 f2bf(float f) {
    union { float f; unsigned u; } v;
    v.f = f;
    unsigned r = v.u + 0x7FFFu + ((v.u >> 16) & 1u);
    return (u16)(r >> 16);
}

__device__ __forceinline__ void async_copy16(const u16* g, u16* l) {
    __builtin_amdgcn_global_load_lds(
        (const __attribute__((address_space(1))) void*)g,
        (__attribute__((address_space(3))) void*)l,
        16, 0, 0);
}

// ---------------------------------------------------------------------------
// prep: blocks [0,4096) convert x fp32->bf16; blocks [4096,8192) build W_eff.
// ---------------------------------------------------------------------------
__global__ void prep_kernel(const float* __restrict__ x, u16* __restrict__ xb,
                            const float* __restrict__ wr, const float* __restrict__ wi,
                            const float* __restrict__ wj, const float* __restrict__ wk,
                            u16* __restrict__ wb) {
    const int b = blockIdx.x;
    if (b < 4096) {
        const int n4 = (QM * QK) / 4;
        for (int i = b * blockDim.x + threadIdx.x; i < n4; i += 4096 * blockDim.x) {
            float4 v = reinterpret_cast<const float4*>(x)[i];
            ushort4 o;
            o.x = f2bf(v.x); o.y = f2bf(v.y); o.z = f2bf(v.z); o.w = f2bf(v.w);
            reinterpret_cast<ushort4*>(xb)[i] = o;
        }
    } else {
        int i = (b - 4096) * blockDim.x + threadIdx.x;   // [0, QN*QK/4)
        int n = i >> 9;
        int p = i & 511;
        int q = n >> 2, co = n & 3;
        int base = (q << 9) + p;
        float r  = wr[base], ii = wi[base], jj = wj[base], kk = wk[base];
        float e0, e1, e2, e3;
        if      (co == 0) { e0 = r;  e1 = -ii; e2 = -jj; e3 = -kk; }
        else if (co == 1) { e0 = ii; e1 = r;   e2 = -jj; e3 = kk;  }
        else if (co == 2) { e0 = jj; e1 = ii;  e2 = r;   e3 = -kk; }
        else              { e0 = kk; e1 = -ii; e2 = jj;  e3 = r;   }
        ushort4 o;
        o.x = f2bf(e0); o.y = f2bf(e1); o.z = f2bf(e2); o.w = f2bf(e3);
        reinterpret_cast<ushort4*>(wb)[(n << 9) + p] = o;
    }
}

// ---------------------------------------------------------------------------
// LDS (u16): A bufs [0,32768) = 2 x 16384; B bufs [32768,81920) = 3 x 16384.
// Buf = 256 rows x 64 cols; physical 16B-chunk (r,cp) holds logical
// (r, cp ^ (r&7)) [involution, both-sides swizzle].
// Per K-tile t: read A-buf t&1, B-buf t%3; stage A(t+1)->(t+1)&1 at exec
// positions 0/1, B(t+2)->(t+2)%3 at positions 2/3. One end-of-tile sync.
// Race-safety identical to R7:
//   [1] A(t+1) dest buf^1: tile-(t-1) readers drained at t-1's end sync;
//       residency for t+1 via end vmcnt(4).
//   [2] B(t+2) dest (t+2)%3 disjoint from read buf t%3 and (t+1)%3;
//       buf t%3 next written at t+1 (B(t+3)), after my reads drained.
//   [3] end-of-tile queue (per wave, both stagger groups — stages are bound
//       to execution position): [B(t+1)x4, A(t+1)x4, B(t+2)x4]; vmcnt(4)
//       drains the 8 oldest => tile t+1 fully resident.
// Stagger: all clusters read only resident buffers, so intra-tile cluster
// order is free; acc accumulation order changes (fp-safe, margin 0.0625 vs
// 0.221).
// ---------------------------------------------------------------------------
__global__ __launch_bounds__(512, 2) void qgemm_kernel(const u16* __restrict__ A,
                                                       const u16* __restrict__ B,
                                                       const float* __restrict__ bias,
                                                       float* __restrict__ C) {
    __shared__ __align__(16) u16 L[81920];      // 160 KB

    const int bid = blockIdx.x;                 // 512 blocks, %8==0
    const int swz = (bid & 7) * 64 + (bid >> 3);
    const int bm = swz >> 3;                    // 0..63
    const int bn = swz & 7;                     // 0..7

    const int tid = threadIdx.x;
    const int wid = tid >> 6, lane = tid & 63;
    const int wm = wid >> 2, wn = wid & 3;
    const int lr = lane & 15, lg = lane >> 4;

    const u16* Asrc = A + (size_t)bm * 256 * QK;
    const u16* Bsrc = B + (size_t)bn * 256 * QK;

    // staging: half-tile = 128 rows x 64 cols; thread covers rows {rA, rA+64}
    const int rA  = tid >> 3;                        // 0..63
    const int clA = ((tid & 7) ^ (rA & 7)) << 3;     // pre-swizzled global col
    const size_t soff = (size_t)rA * QK + clA;

    f32x4 acc[8][4];
#pragma unroll
    for (int i = 0; i < 8; ++i)
#pragma unroll
        for (int j = 0; j < 4; ++j)
            acc[i][j] = (f32x4){0.f, 0.f, 0.f, 0.f};

    auto stage = [&](const u16* src, int lbase, int k0) {
#pragma unroll
        for (int o = 0; o < 2; ++o)
            async_copy16(src + (size_t)(o * 64) * QK + k0 + soff,
                         &L[lbase + o * 4096 + wid * 512]);
    };

    auto rdA = [&](const u16* LA, int mf, int ks) -> bf16x8 {
        const int r = wm * 128 + mf * 16 + lr;
        const int c = ((ks * 4 + lg) ^ (r & 7)) << 3;
        return *(const bf16x8*)&LA[r * 64 + c];
    };
    auto rdB = [&](const u16* LB, int nf, int ks) -> bf16x8 {
        const int r = wn * 64 + nf * 16 + lr;
        const int c = ((ks * 4 + lg) ^ (r & 7)) << 3;
        return *(const bf16x8*)&LB[r * 64 + c];
    };

    // ab, bt, bt2 are LITERAL constants at every call site.
    auto doTile = [&](const int ab, const int bt, const int bt2, const int t)
        __attribute__((always_inline)) {
        const u16* LA = &L[ab * 16384];
        const u16* LB = &L[32768 + bt * 16384];
        const int tw1 = (t + 1) & 31, tw2 = (t + 2) & 31;
        const int oA = (ab ^ 1) * 16384;          // A dest buf
        const int oB = 32768 + bt2 * 16384;       // B dest buf

        // one cluster: optional B-frag read, 4 A-frag reads, positional
        // stage, setprio-wrapped 16 MFMA. ks/mh/sp are literals at each call.
        auto cluster = [&](const int ks, const int mh, const int sp,
                           const bool loadB, bf16x8 (&bv)[4])
            __attribute__((always_inline)) {
            bf16x8 av[4];
            if (loadB)
#pragma unroll
                for (int nf = 0; nf < 4; ++nf) bv[nf] = rdB(LB, nf, ks);
#pragma unroll
            for (int mf = 0; mf < 4; ++mf) av[mf] = rdA(LA, mh * 4 + mf, ks);
            if      (sp == 0) stage(Asrc,            oA,        tw1 * 64);
            else if (sp == 1) stage(Asrc + 128 * QK, oA + 8192, tw1 * 64);
            else if (sp == 2) stage(Bsrc,            oB,        tw2 * 64);
            else              stage(Bsrc + 128 * QK, oB + 8192, tw2 * 64);
            __builtin_amdgcn_s_setprio(1);
#pragma unroll
            for (int mf = 0; mf < 4; ++mf)
#pragma unroll
                for (int nf = 0; nf < 4; ++nf)
                    acc[mh * 4 + mf][nf] = __builtin_amdgcn_mfma_f32_16x16x32_bf16(
                        av[mf], bv[nf], acc[mh * 4 + mf][nf], 0, 0, 0);
            __builtin_amdgcn_s_setprio(0);
        };

        bf16x8 b0[4], b1[4];
        if (wid < 4) {               // group 0: ks0 half first
            cluster(0, 0, 0, true,  b0);
            cluster(0, 1, 1, false, b0);
            cluster(1, 0, 2, true,  b1);
            cluster(1, 1, 3, false, b1);
        } else {                     // group 1: ks1 half first
            cluster(1, 0, 0, true,  b1);
            cluster(1, 1, 1, false, b1);
            cluster(0, 0, 2, true,  b0);
            cluster(0, 1, 3, false, b0);
        }

        // single sync point: tile t+1 resident, all my LDS reads drained
        asm volatile("s_waitcnt lgkmcnt(0) vmcnt(4)" ::: "memory");
        __builtin_amdgcn_s_barrier();
    };

    // prologue: A(0)->Abuf0, B(0)->Bbuf0, B(1)->Bbuf1
    stage(Asrc,            0,             0);
    stage(Asrc + 128 * QK, 8192,          0);
    stage(Bsrc,            32768,             0);
    stage(Bsrc + 128 * QK, 32768 + 8192,      0);
    stage(Bsrc,            32768 + 16384,        64);
    stage(Bsrc + 128 * QK, 32768 + 16384 + 8192, 64);
    asm volatile("s_waitcnt vmcnt(4)" ::: "memory");   // A(0),B(0) resident
    __builtin_amdgcn_s_barrier();

    // 32 tiles = 5 x 6 (lcm of rings 2,3) + 2 tail; literal ring indices.
    for (int t = 0; t < 30; t += 6) {
        doTile(0, 0, 2, t);
        doTile(1, 1, 0, t + 1);
        doTile(0, 2, 1, t + 2);
        doTile(1, 0, 2, t + 3);
        doTile(0, 1, 0, t + 4);
        doTile(1, 2, 1, t + 5);
    }
    doTile(0, 0, 2, 30);
    doTile(1, 1, 0, 31);

    // epilogue: C/D layout col = lane&15, row = (lane>>4)*4 + reg
    const int colbase = bn * 256 + wn * 64;
    const int rowbase = bm * 256 + wm * 128;
    float bsv[4];
#pragma unroll
    for (int nf = 0; nf < 4; ++nf) bsv[nf] = bias[colbase + nf * 16 + lr];
    float* Cb = C + (size_t)rowbase * QN + colbase;
#pragma unroll
    for (int mf = 0; mf < 8; ++mf)
#pragma unroll
        for (int nf = 0; nf < 4; ++nf)
#pragma unroll
            for (int v = 0; v < 4; ++v)
                Cb[(size_t)(mf * 16 + lg * 4 + v) * QN + nf * 16 + lr] = acc[mf][nf][v] + bsv[nf];
}

// ---------------------------------------------------------------------------
extern "C" void kernel_launch(void* const* d_in, const int* in_sizes, int n_in,
                              void* d_out, int out_size, void* d_ws, size_t ws_size,
                              hipStream_t stream) {
    const float* x    = (const float*)d_in[0];
    const float* wr   = (const float*)d_in[1];
    const float* wi   = (const float*)d_in[2];
    const float* wj   = (const float*)d_in[3];
    const float* wk   = (const float*)d_in[4];
    const float* bias = (const float*)d_in[5];
    float* out = (float*)d_out;

    u16* xb = (u16*)d_ws;                                   // 64 MB
    u16* wb = (u16*)((char*)d_ws + (size_t)QM * QK * 2);    // 8 MB

    prep_kernel<<<8192, 256, 0, stream>>>(x, xb, wr, wi, wj, wk, wb);
    qgemm_kernel<<<512, 512, 0, stream>>>(xb, wb, bias, out);
}

// Round 10
// 218.409 us; speedup vs baseline: 3.2766x; 3.2766x over previous
//
#include <hip/hip_runtime.h>

// ---------------------------------------------------------------------------
// QuaternionLinear == one dense GEMM: out[M,N] = x[M,K] @ W_eff[N,K]^T + bias
//   M = 16384 (B*S), N = 2048 (OUT_F), K = 2048 (IN_F)
// R10: prep shrinks to W_eff only; x fp32->bf16 conversion FUSED into
// qgemm's A-staging (reg-stage: 2x global_load_dwordx4 -> cvt -> swizzled
// ds_write_b128). Saves the 64MB xb write + 64MB xb read (~20us HBM) and
// ~25us of prep dispatch. B stays on global_load_lds.
// qgemm core = R7 (best verified): 256x256 tile, BK=64, 8 waves (2x4),
// per-wave 128x64, 16x16x32 MFMA, A 2-ring + B 3-ring LDS (160KB), chunk-
// XOR swizzle (T2), ONE sync point per K-tile w/ counted vmcnt (T3/T4),
// literal ring indices (6-tile unroll), XCD swizzle (T1), no setprio.
// R9 lesson: no wave-divergent tile bodies (acc spilled -> 1.25GB scratch).
// ---------------------------------------------------------------------------

typedef unsigned short u16;
typedef __bf16 bf16x8 __attribute__((ext_vector_type(8)));
typedef unsigned short u16x8 __attribute__((ext_vector_type(8)));
typedef float f32x4 __attribute__((ext_vector_type(4)));

#define QM 16384
#define QN 2048
#define QK 2048

__device__ __forceinline__ u16 f2bf(float f) {
    union { float f; unsigned u; } v;
    v.f = f;
    unsigned r = v.u + 0x7FFFu + ((v.u >> 16) & 1u);
    return (u16)(r >> 16);
}

__device__ __forceinline__ void async_copy16(const u16* g, u16* l) {
    __builtin_amdgcn_global_load_lds(
        (const __attribute__((address_space(1))) void*)g,
        (__attribute__((address_space(3))) void*)l,
        16, 0, 0);
}

// ---------------------------------------------------------------------------
// prep: build W_eff only (2048x2048 bf16, row-major). ~12MB traffic.
// ---------------------------------------------------------------------------
__global__ void prepw_kernel(const float* __restrict__ wr, const float* __restrict__ wi,
                             const float* __restrict__ wj, const float* __restrict__ wk,
                             u16* __restrict__ wb) {
    int i = blockIdx.x * blockDim.x + threadIdx.x;   // [0, QN*QK/4)
    if (i >= QN * (QK / 4)) return;
    int n = i >> 9;
    int p = i & 511;
    int q = n >> 2, co = n & 3;
    int base = (q << 9) + p;
    float r  = wr[base], ii = wi[base], jj = wj[base], kk = wk[base];
    float e0, e1, e2, e3;
    if      (co == 0) { e0 = r;  e1 = -ii; e2 = -jj; e3 = -kk; }
    else if (co == 1) { e0 = ii; e1 = r;   e2 = -jj; e3 = kk;  }
    else if (co == 2) { e0 = jj; e1 = ii;  e2 = r;   e3 = -kk; }
    else              { e0 = kk; e1 = -ii; e2 = jj;  e3 = r;   }
    ushort4 o;
    o.x = f2bf(e0); o.y = f2bf(e1); o.z = f2bf(e2); o.w = f2bf(e3);
    reinterpret_cast<ushort4*>(wb)[(n << 9) + p] = o;
}

// ---------------------------------------------------------------------------
// LDS (u16): A bufs [0,32768) = 2 x 16384; B bufs [32768,81920) = 3 x 16384.
// Buf = 256 rows x 64 cols; physical 16B-chunk (r,cp) holds logical
// (r, cp ^ (r&7)) [involution].
// Per K-tile t: read A-buf t&1, B-buf t%3.
//   cluster0: issue A(t+1) fp32 loads (8x dwordx4, pre-swizzled logical col)
//   cluster2/3: stage B(t+2) halves via global_load_lds
//   tail: cvt A-loads -> 4x ds_write_b128 into A-buf (t+1)&1 (linear dest,
//         same address math as the old gload_lds dest)
//   end: lgkm(0)+vmcnt(4)+barrier (single sync point).
// Race-safety (as R7):
//   [1] A(t+1) dest buf^1: tile-(t-1) readers drained at t-1's end sync;
//       ds_writes complete under my end lgkm(0), visible after barrier.
//   [2] B(t+2) dest (t+2)%3 disjoint from read buf t%3 and (t+1)%3.
//   [3] vmcnt ledger: per tile issue order [Afp32 x8, B(t+2) x4]; consuming
//       the A-loads (cvt) auto-drains all older entries incl. B(t+1); at the
//       end sync outstanding = B(t+2) x4 -> vmcnt(4) holds them in flight.
// ---------------------------------------------------------------------------
__global__ __launch_bounds__(512, 2) void qgemm_kernel(const float* __restrict__ X,
                                                       const u16* __restrict__ B,
                                                       const float* __restrict__ bias,
                                                       float* __restrict__ C) {
    __shared__ __align__(16) u16 L[81920];      // 160 KB

    const int bid = blockIdx.x;                 // 512 blocks, %8==0
    const int swz = (bid & 7) * 64 + (bid >> 3);
    const int bm = swz >> 3;                    // 0..63
    const int bn = swz & 7;                     // 0..7

    const int tid = threadIdx.x;
    const int wid = tid >> 6, lane = tid & 63;
    const int wm = wid >> 2, wn = wid & 3;
    const int lr = lane & 15, lg = lane >> 4;

    const float* Afp = X + (size_t)bm * 256 * QK;
    const u16*  Bsrc = B + (size_t)bn * 256 * QK;

    // staging geometry: thread owns physical chunk (row rA + {0,64,128,192},
    // chunk tid&7); logical col is pre-swizzled.
    const int rA   = tid >> 3;                        // 0..63
    const int aclf = ((tid & 7) ^ (rA & 7)) << 3;     // logical col (elems)
    const size_t bsoff = (size_t)rA * QK + aclf;      // B gload src offset
    const int ldst = wid * 512 + lane * 8;            // linear LDS dest (elems)

    f32x4 acc[8][4];
#pragma unroll
    for (int i = 0; i < 8; ++i)
#pragma unroll
        for (int j = 0; j < 4; ++j)
            acc[i][j] = (f32x4){0.f, 0.f, 0.f, 0.f};

    auto stageB = [&](const u16* src, int lbase, int k0) {
#pragma unroll
        for (int o = 0; o < 2; ++o)
            async_copy16(src + (size_t)(o * 64) * QK + k0 + bsoff,
                         &L[lbase + o * 4096 + wid * 512]);
    };

    // issue A(t+1) fp32 loads: chunk c -> row rA + 64*(c&1) + 128*(c>>1)
    auto loadA = [&](f32x4 (&af)[4][2], int k0) {
#pragma unroll
        for (int c = 0; c < 4; ++c) {
            const float* s = Afp + (size_t)(rA + (c & 1) * 64 + (c >> 1) * 128) * QK + aclf + k0;
            af[c][0] = *(const f32x4*)(s);
            af[c][1] = *(const f32x4*)(s + 4);
        }
    };
    // cvt + swizzled ds_write into A buf at lbase
    auto writeA = [&](f32x4 (&af)[4][2], int lbase) {
#pragma unroll
        for (int c = 0; c < 4; ++c) {
            u16x8 p;
#pragma unroll
            for (int e = 0; e < 4; ++e) p[e]     = f2bf(af[c][0][e]);
#pragma unroll
            for (int e = 0; e < 4; ++e) p[4 + e] = f2bf(af[c][1][e]);
            *reinterpret_cast<u16x8*>(&L[lbase + (c >> 1) * 8192 + (c & 1) * 4096 + ldst]) = p;
        }
    };

    auto rdA = [&](const u16* LA, int mf, int ks) -> bf16x8 {
        const int r = wm * 128 + mf * 16 + lr;
        const int c = ((ks * 4 + lg) ^ (r & 7)) << 3;
        return *(const bf16x8*)&LA[r * 64 + c];
    };
    auto rdB = [&](const u16* LB, int nf, int ks) -> bf16x8 {
        const int r = wn * 64 + nf * 16 + lr;
        const int c = ((ks * 4 + lg) ^ (r & 7)) << 3;
        return *(const bf16x8*)&LB[r * 64 + c];
    };

    // ab, bt, bt2 are LITERAL constants at every call site.
    auto doTile = [&](const int ab, const int bt, const int bt2, const int t)
        __attribute__((always_inline)) {
        const u16* LA = &L[ab * 16384];
        const u16* LB = &L[32768 + bt * 16384];
        const int tw1 = (t + 1) & 31, tw2 = (t + 2) & 31;
        const int oA = (ab ^ 1) * 16384;          // A dest buf
        const int oB = 32768 + bt2 * 16384;       // B dest buf

        bf16x8 a0[4], a1[4], b0[4], b1[4];
        f32x4 af[4][2];

        // cluster 0 (ks0, mh0): + issue A(t+1) fp32 loads
#pragma unroll
        for (int nf = 0; nf < 4; ++nf) b0[nf] = rdB(LB, nf, 0);
#pragma unroll
        for (int mf = 0; mf < 4; ++mf) a0[mf] = rdA(LA, mf, 0);
        loadA(af, tw1 * 64);
#pragma unroll
        for (int mf = 0; mf < 4; ++mf)
#pragma unroll
            for (int nf = 0; nf < 4; ++nf)
                acc[mf][nf] = __builtin_amdgcn_mfma_f32_16x16x32_bf16(a0[mf], b0[nf], acc[mf][nf], 0, 0, 0);

        // cluster 1 (ks0, mh1): + B[ks1] frag reads
#pragma unroll
        for (int mf = 0; mf < 4; ++mf) a1[mf] = rdA(LA, 4 + mf, 0);
#pragma unroll
        for (int nf = 0; nf < 4; ++nf) b1[nf] = rdB(LB, nf, 1);
#pragma unroll
        for (int mf = 0; mf < 4; ++mf)
#pragma unroll
            for (int nf = 0; nf < 4; ++nf)
                acc[4 + mf][nf] = __builtin_amdgcn_mfma_f32_16x16x32_bf16(a1[mf], b0[nf], acc[4 + mf][nf], 0, 0, 0);

        // cluster 2 (ks1, mh0): + stage B(t+2) half0
#pragma unroll
        for (int mf = 0; mf < 4; ++mf) a0[mf] = rdA(LA, mf, 1);
        stageB(Bsrc, oB, tw2 * 64);
#pragma unroll
        for (int mf = 0; mf < 4; ++mf)
#pragma unroll
            for (int nf = 0; nf < 4; ++nf)
                acc[mf][nf] = __builtin_amdgcn_mfma_f32_16x16x32_bf16(a0[mf], b1[nf], acc[mf][nf], 0, 0, 0);

        // cluster 3 (ks1, mh1): + stage B(t+2) half1
#pragma unroll
        for (int mf = 0; mf < 4; ++mf) a1[mf] = rdA(LA, 4 + mf, 1);
        stageB(Bsrc + 128 * QK, oB + 8192, tw2 * 64);
#pragma unroll
        for (int mf = 0; mf < 4; ++mf)
#pragma unroll
            for (int nf = 0; nf < 4; ++nf)
                acc[4 + mf][nf] = __builtin_amdgcn_mfma_f32_16x16x32_bf16(a1[mf], b1[nf], acc[4 + mf][nf], 0, 0, 0);

        // tail: convert + write A(t+1) (auto vmcnt wait on af drains all
        // older VMEM incl. B(t+1); ds_writes covered by end lgkm(0))
        writeA(af, oA);

        // single sync point: tile t+1 resident, all my LDS ops drained
        asm volatile("s_waitcnt lgkmcnt(0) vmcnt(4)" ::: "memory");
        __builtin_amdgcn_s_barrier();
    };

    // prologue: A(0)->Abuf0 (reg-staged), B(0)->Bbuf0, B(1)->Bbuf1
    {
        f32x4 af[4][2];
        loadA(af, 0);
        stageB(Bsrc,            32768,             0);
        stageB(Bsrc + 128 * QK, 32768 + 8192,      0);
        stageB(Bsrc,            32768 + 16384,        64);
        stageB(Bsrc + 128 * QK, 32768 + 16384 + 8192, 64);
        writeA(af, 0);                                  // waits A loads (auto)
        asm volatile("s_waitcnt lgkmcnt(0) vmcnt(4)" ::: "memory"); // B(0) resident
        __builtin_amdgcn_s_barrier();
    }

    // 32 tiles = 5 x 6 (lcm of rings 2,3) + 2 tail; literal ring indices.
    for (int t = 0; t < 30; t += 6) {
        doTile(0, 0, 2, t);
        doTile(1, 1, 0, t + 1);
        doTile(0, 2, 1, t + 2);
        doTile(1, 0, 2, t + 3);
        doTile(0, 1, 0, t + 4);
        doTile(1, 2, 1, t + 5);
    }
    doTile(0, 0, 2, 30);
    doTile(1, 1, 0, 31);

    // epilogue: C/D layout col = lane&15, row = (lane>>4)*4 + reg
    const int colbase = bn * 256 + wn * 64;
    const int rowbase = bm * 256 + wm * 128;
    float bsv[4];
#pragma unroll
    for (int nf = 0; nf < 4; ++nf) bsv[nf] = bias[colbase + nf * 16 + lr];
    float* Cb = C + (size_t)rowbase * QN + colbase;
#pragma unroll
    for (int mf = 0; mf < 8; ++mf)
#pragma unroll
        for (int nf = 0; nf < 4; ++nf)
#pragma unroll
            for (int v = 0; v < 4; ++v)
                Cb[(size_t)(mf * 16 + lg * 4 + v) * QN + nf * 16 + lr] = acc[mf][nf][v] + bsv[nf];
}

// ---------------------------------------------------------------------------
extern "C" void kernel_launch(void* const* d_in, const int* in_sizes, int n_in,
                              void* d_out, int out_size, void* d_ws, size_t ws_size,
                              hipStream_t stream) {
    const float* x    = (const float*)d_in[0];
    const float* wr   = (const float*)d_in[1];
    const float* wi   = (const float*)d_in[2];
    const float* wj   = (const float*)d_in[3];
    const float* wk   = (const float*)d_in[4];
    const float* bias = (const float*)d_in[5];
    float* out = (float*)d_out;

    u16* wb = (u16*)d_ws;                                   // 8 MB (W_eff)

    prepw_kernel<<<4096, 256, 0, stream>>>(wr, wi, wj, wk, wb);
    qgemm_kernel<<<512, 512, 0, stream>>>(x, wb, bias, out);
}

// Round 11
// 170.074 us; speedup vs baseline: 4.2078x; 1.2842x over previous
//
#include <hip/hip_runtime.h>

// ---------------------------------------------------------------------------
// QuaternionLinear == one dense GEMM: out[M,N] = x[M,K] @ W_eff[N,K]^T + bias
//   M = 16384 (B*S), N = 2048 (OUT_F), K = 2048 (IN_F)
// Pipeline: prep (fp32->bf16 x + build W_eff) ; qgemm.
// R11 = R7 structure + mfma_f32_32x32x16_bf16 (2495 TF ubench vs ~2100 for
// 16x16x32, m119): ~17% fewer MFMA-pipe cycles at identical LDS traffic
// (24 b128 frag reads/wave/tile both ways). R5-R7 showed the tile time ~
// serialized sum of MFMA pipe (2480cyc) + LDS pipe (~2250cyc); shrinking
// the MFMA term is the remaining lever that doesn't touch the schedule.
// Kept: 256x256 tile, BK=64, 8 waves (2x4), per-wave 128x64, A 2-ring +
// B 3-ring LDS (160KB), chunk-XOR swizzle (T2), ONE sync/tile w/ counted
// vmcnt(4) (T3/T4), literal ring indices (6-tile unroll), XCD swizzle (T1),
// fused prep, no setprio, no divergent tile bodies (R9 lesson).
// Layouts (32x32x16): A row=lane&31, k=(lane>>5)*8+e; B col=lane&31 same k
// (symmetry with the verified 16x16x32 mapping); C/D col=lane&31,
// row=(reg&3)+8*(reg>>2)+4*(lane>>5) [m74/m101].
// ---------------------------------------------------------------------------

typedef unsigned short u16;
typedef __bf16 bf16x8 __attribute__((ext_vector_type(8)));
typedef float f32x16 __attribute__((ext_vector_type(16)));

#define QM 16384
#define QN 2048
#define QK 2048

__device__ __forceinline__ u16 f2bf(float f) {
    union { float f; unsigned u; } v;
    v.f = f;
    unsigned r = v.u + 0x7FFFu + ((v.u >> 16) & 1u);
    return (u16)(r >> 16);
}

__device__ __forceinline__ void async_copy16(const u16* g, u16* l) {
    __builtin_amdgcn_global_load_lds(
        (const __attribute__((address_space(1))) void*)g,
        (__attribute__((address_space(3))) void*)l,
        16, 0, 0);
}

// ---------------------------------------------------------------------------
// prep: blocks [0,4096) convert x fp32->bf16; blocks [4096,8192) build W_eff.
// ---------------------------------------------------------------------------
__global__ void prep_kernel(const float* __restrict__ x, u16* __restrict__ xb,
                            const float* __restrict__ wr, const float* __restrict__ wi,
                            const float* __restrict__ wj, const float* __restrict__ wk,
                            u16* __restrict__ wb) {
    const int b = blockIdx.x;
    if (b < 4096) {
        const int n4 = (QM * QK) / 4;
        for (int i = b * blockDim.x + threadIdx.x; i < n4; i += 4096 * blockDim.x) {
            float4 v = reinterpret_cast<const float4*>(x)[i];
            ushort4 o;
            o.x = f2bf(v.x); o.y = f2bf(v.y); o.z = f2bf(v.z); o.w = f2bf(v.w);
            reinterpret_cast<ushort4*>(xb)[i] = o;
        }
    } else {
        int i = (b - 4096) * blockDim.x + threadIdx.x;   // [0, QN*QK/4)
        int n = i >> 9;
        int p = i & 511;
        int q = n >> 2, co = n & 3;
        int base = (q << 9) + p;
        float r  = wr[base], ii = wi[base], jj = wj[base], kk = wk[base];
        float e0, e1, e2, e3;
        if      (co == 0) { e0 = r;  e1 = -ii; e2 = -jj; e3 = -kk; }
        else if (co == 1) { e0 = ii; e1 = r;   e2 = -jj; e3 = kk;  }
        else if (co == 2) { e0 = jj; e1 = ii;  e2 = r;   e3 = -kk; }
        else              { e0 = kk; e1 = -ii; e2 = jj;  e3 = r;   }
        ushort4 o;
        o.x = f2bf(e0); o.y = f2bf(e1); o.z = f2bf(e2); o.w = f2bf(e3);
        reinterpret_cast<ushort4*>(wb)[(n << 9) + p] = o;
    }
}

// ---------------------------------------------------------------------------
// LDS (u16): A bufs [0,32768) = 2 x 16384; B bufs [32768,81920) = 3 x 16384.
// Buf = 256 rows x 64 cols; physical 16B-chunk (r,cp) holds logical
// (r, cp ^ (r&7)) [involution, both-sides swizzle].
// Per K-tile t: read A-buf t&1, B-buf t%3; stage A(t+1)->(t+1)&1 at clusters
// 0/1, B(t+2)->(t+2)%3 at clusters 2/3. One end-of-tile sync:
// lgkm(0)+vmcnt(4)+barrier. Race proof identical to R7:
//   [1] A(t+1) dest buf^1: tile-(t-1) readers drained at t-1's end sync;
//       residency for t+1 via end vmcnt(4).
//   [2] B(t+2) dest (t+2)%3 disjoint from read buf t%3 and (t+1)%3;
//       buf t%3 next written at t+1 (B(t+3)), after my reads drained.
//   [3] end queue = [B(t+1)x4, A(t+1)x4, B(t+2)x4]; vmcnt(4) => tile t+1
//       fully resident, B(t+2) stays in flight.
// ---------------------------------------------------------------------------
__global__ __launch_bounds__(512, 2) void qgemm_kernel(const u16* __restrict__ A,
                                                       const u16* __restrict__ B,
                                                       const float* __restrict__ bias,
                                                       float* __restrict__ C) {
    __shared__ __align__(16) u16 L[81920];      // 160 KB

    const int bid = blockIdx.x;                 // 512 blocks, %8==0
    const int swz = (bid & 7) * 64 + (bid >> 3);
    const int bm = swz >> 3;                    // 0..63
    const int bn = swz & 7;                     // 0..7

    const int tid = threadIdx.x;
    const int wid = tid >> 6, lane = tid & 63;
    const int wm = wid >> 2, wn = wid & 3;
    const int lr = lane & 31;                   // 32-row/col lane index
    const int hi = lane >> 5;                   // k-half
    
    const u16* Asrc = A + (size_t)bm * 256 * QK;
    const u16* Bsrc = B + (size_t)bn * 256 * QK;

    // staging: half-tile = 128 rows x 64 cols; thread covers rows {rA, rA+64}
    const int rA  = tid >> 3;                        // 0..63
    const int clA = ((tid & 7) ^ (rA & 7)) << 3;     // pre-swizzled global col
    const size_t soff = (size_t)rA * QK + clA;

    f32x16 acc[4][2];
#pragma unroll
    for (int i = 0; i < 4; ++i)
#pragma unroll
        for (int j = 0; j < 2; ++j)
            acc[i][j] = (f32x16){0.f};

    auto stage = [&](const u16* src, int lbase, int k0) {
#pragma unroll
        for (int o = 0; o < 2; ++o)
            async_copy16(src + (size_t)(o * 64) * QK + k0 + soff,
                         &L[lbase + o * 4096 + wid * 512]);
    };

    // 32x32x16 A-frag: row = wm*128 + mt*32 + lr; k-chunk = s*2 + hi
    auto rdA = [&](const u16* LA, int mt, int s) -> bf16x8 {
        const int r = wm * 128 + mt * 32 + lr;
        const int c = ((s * 2 + hi) ^ (r & 7)) << 3;
        return *(const bf16x8*)&LA[r * 64 + c];
    };
    // 32x32x16 B-frag: ncol(row in B^T tile) = wn*64 + nt*32 + lr
    auto rdB = [&](const u16* LB, int nt, int s) -> bf16x8 {
        const int r = wn * 64 + nt * 32 + lr;
        const int c = ((s * 2 + hi) ^ (r & 7)) << 3;
        return *(const bf16x8*)&LB[r * 64 + c];
    };

    // ab, bt, bt2 are LITERAL constants at every call site.
    auto doTile = [&](const int ab, const int bt, const int bt2, const int t)
        __attribute__((always_inline)) {
        const u16* LA = &L[ab * 16384];
        const u16* LB = &L[32768 + bt * 16384];
        const int tw1 = (t + 1) & 31, tw2 = (t + 2) & 31;
        const int oA = (ab ^ 1) * 16384;          // A dest buf
        const int oB = 32768 + bt2 * 16384;       // B dest buf

        // 4 clusters = K-steps s=0..3: 2 B-frag + 4 A-frag reads, positional
        // stage, 8 MFMA (4 mt x 2 nt). No barriers between clusters.
#pragma unroll
        for (int s = 0; s < 4; ++s) {
            bf16x8 bv[2], av[4];
#pragma unroll
            for (int nt = 0; nt < 2; ++nt) bv[nt] = rdB(LB, nt, s);
#pragma unroll
            for (int mt = 0; mt < 4; ++mt) av[mt] = rdA(LA, mt, s);
            if      (s == 0) stage(Asrc,            oA,        tw1 * 64);
            else if (s == 1) stage(Asrc + 128 * QK, oA + 8192, tw1 * 64);
            else if (s == 2) stage(Bsrc,            oB,        tw2 * 64);
            else             stage(Bsrc + 128 * QK, oB + 8192, tw2 * 64);
#pragma unroll
            for (int mt = 0; mt < 4; ++mt)
#pragma unroll
                for (int nt = 0; nt < 2; ++nt)
                    acc[mt][nt] = __builtin_amdgcn_mfma_f32_32x32x16_bf16(
                        av[mt], bv[nt], acc[mt][nt], 0, 0, 0);
        }

        // single sync point: tile t+1 resident, all my LDS reads drained
        asm volatile("s_waitcnt lgkmcnt(0) vmcnt(4)" ::: "memory");
        __builtin_amdgcn_s_barrier();
    };

    // prologue: A(0)->Abuf0, B(0)->Bbuf0, B(1)->Bbuf1
    stage(Asrc,            0,             0);
    stage(Asrc + 128 * QK, 8192,          0);
    stage(Bsrc,            32768,             0);
    stage(Bsrc + 128 * QK, 32768 + 8192,      0);
    stage(Bsrc,            32768 + 16384,        64);
    stage(Bsrc + 128 * QK, 32768 + 16384 + 8192, 64);
    asm volatile("s_waitcnt vmcnt(4)" ::: "memory");   // A(0),B(0) resident
    __builtin_amdgcn_s_barrier();

    // 32 tiles = 5 x 6 (lcm of rings 2,3) + 2 tail; literal ring indices.
    for (int t = 0; t < 30; t += 6) {
        doTile(0, 0, 2, t);
        doTile(1, 1, 0, t + 1);
        doTile(0, 2, 1, t + 2);
        doTile(1, 0, 2, t + 3);
        doTile(0, 1, 0, t + 4);
        doTile(1, 2, 1, t + 5);
    }
    doTile(0, 0, 2, 30);
    doTile(1, 1, 0, 31);

    // epilogue: 32x32 C/D layout col = lane&31, row = (e&3)+8*(e>>2)+4*hi
    const int colbase = bn * 256 + wn * 64;
    const int rowbase = bm * 256 + wm * 128;
    float bsv[2];
#pragma unroll
    for (int nt = 0; nt < 2; ++nt) bsv[nt] = bias[colbase + nt * 32 + lr];
    float* Cb = C + (size_t)rowbase * QN + colbase;
#pragma unroll
    for (int mt = 0; mt < 4; ++mt)
#pragma unroll
        for (int nt = 0; nt < 2; ++nt)
#pragma unroll
            for (int e = 0; e < 16; ++e) {
                const int ro = mt * 32 + (e & 3) + 8 * (e >> 2) + 4 * hi;
                Cb[(size_t)ro * QN + nt * 32 + lr] = acc[mt][nt][e] + bsv[nt];
            }
}

// ---------------------------------------------------------------------------
extern "C" void kernel_launch(void* const* d_in, const int* in_sizes, int n_in,
                              void* d_out, int out_size, void* d_ws, size_t ws_size,
                              hipStream_t stream) {
    const float* x    = (const float*)d_in[0];
    const float* wr   = (const float*)d_in[1];
    const float* wi   = (const float*)d_in[2];
    const float* wj   = (const float*)d_in[3];
    const float* wk   = (const float*)d_in[4];
    const float* bias = (const float*)d_in[5];
    float* out = (float*)d_out;

    u16* xb = (u16*)d_ws;                                   // 64 MB
    u16* wb = (u16*)((char*)d_ws + (size_t)QM * QK * 2);    // 8 MB

    prep_kernel<<<8192, 256, 0, stream>>>(x, xb, wr, wi, wj, wk, wb);
    qgemm_kernel<<<512, 512, 0, stream>>>(xb, wb, bias, out);
}